// Round 2
// baseline (2012.407 us; speedup 1.0000x reference)
//
#include <hip/hip_runtime.h>
#include <hip/hip_bf16.h>
#include <math.h>

#define B_   8
#define H_   320
#define W_   320
#define HW_  (320*320)

// ---------------------------------------------------------------------------
// Weight repack: [co][ci][ky][kx] fp32  ->  [ci*K*K + ky*K + kx][co] fp32
// ---------------------------------------------------------------------------
__global__ void repack_k(const float* __restrict__ w, float* __restrict__ out,
                         int Cout, int CinKK){
    int i = blockIdx.x*256 + threadIdx.x;
    if (i >= Cout*CinKK) return;
    int co = i / CinKK;
    int t  = i - co*CinKK;
    out[t*Cout + co] = w[i];
}

// ---------------------------------------------------------------------------
// Direct conv: 32x8 spatial tile per block (256 thr), 8-cin LDS chunks.
// IN_BN applies y = relu(x*scale[ci]+shift[ci]) at load (zero halo AFTER bn,
// matching reference zero-padding of the activated tensor).
// OUT_MODE: 0 raw, 1 +bias, 2 tanh(x+bias)
// ---------------------------------------------------------------------------
template<int CIN, int COUT, int K, bool IN_BN, int OUT_MODE>
__global__ __launch_bounds__(256)
void conv_k(const float* __restrict__ in,
            const float* __restrict__ scale, const float* __restrict__ shift,
            const float* __restrict__ w, const float* __restrict__ bias,
            float* __restrict__ out){
    constexpr int PAD = K/2;
    constexpr int LW  = 32 + K - 1;
    constexpr int LH  = 8 + K - 1;
    constexpr int PS  = LW*LH;
    constexpr int CCH = 8;
    __shared__ float lds[CCH*PS];
    float acc[COUT];
    #pragma unroll
    for (int i=0;i<COUT;++i) acc[i] = 0.f;

    const int tid = threadIdx.x;
    const int tx = tid & 31, ty = tid >> 5;
    const int x0 = blockIdx.x*32, y0 = blockIdx.y*8;
    const int b  = blockIdx.z;

    for (int c0=0; c0<CIN; c0+=CCH){
        if (c0) __syncthreads();
        for (int i=tid; i<CCH*PS; i+=256){
            const int pl  = i / PS;
            const int rem = i - pl*PS;
            const int r   = rem / LW;
            const int cc  = rem - r*LW;
            const int gy = y0 + r - PAD, gx = x0 + cc - PAD;
            float v = 0.f;
            if (gy>=0 && gy<H_ && gx>=0 && gx<W_){
                const int ci = c0 + pl;
                const long idx = (((long)b*CIN + ci)*H_ + gy)*W_ + gx;
                v = in[idx];
                if (IN_BN)   v = fmaxf(fmaf(v, scale[ci], shift[ci]), 0.f);
            }
            lds[i] = v;
        }
        __syncthreads();
        for (int pl=0; pl<CCH; ++pl){
            const float* wb = w + (long)(c0+pl)*(K*K*COUT);
            const float* lp = lds + pl*PS + ty*LW + tx;
            #pragma unroll
            for (int ky=0; ky<K; ++ky){
                #pragma unroll
                for (int kx=0; kx<K; ++kx){
                    const float v = lp[ky*LW + kx];
                    const float* wt = wb + (ky*K+kx)*COUT;
                    #pragma unroll
                    for (int co=0; co<COUT; ++co)
                        acc[co] = fmaf(v, wt[co], acc[co]);
                }
            }
        }
    }
    const int gy = y0+ty, gx = x0+tx;
    #pragma unroll
    for (int co=0; co<COUT; ++co){
        float o = acc[co];
        if (OUT_MODE >= 1) o += bias[co];
        if (OUT_MODE == 2) o = tanhf(o);
        out[(((long)b*COUT+co)*H_+gy)*W_+gx] = o;
    }
}

// ---------------------------------------------------------------------------
// Per-channel sum / sumsq (training-mode BN stats), atomic partials.
// grid = (C, NSLICE)
// ---------------------------------------------------------------------------
__global__ void bn_stats_k(const float* __restrict__ in,
                           float* __restrict__ sum, float* __restrict__ sumsq,
                           int C){
    const int c = blockIdx.x;
    float s=0.f, s2=0.f;
    for (int b=0;b<B_;++b){
        const float* src = in + ((long)b*C + c)*HW_;
        for (int p = blockIdx.y*256 + threadIdx.x; p < HW_; p += gridDim.y*256){
            float v = src[p]; s += v; s2 = fmaf(v, v, s2);
        }
    }
    #pragma unroll
    for (int off=32; off; off>>=1){
        s  += __shfl_down(s,  off, 64);
        s2 += __shfl_down(s2, off, 64);
    }
    if ((threadIdx.x & 63) == 0){
        atomicAdd(&sum[c], s);
        atomicAdd(&sumsq[c], s2);
    }
}

__global__ void bn_fin_k(const float* __restrict__ sum, const float* __restrict__ sumsq,
                         const float* __restrict__ gamma, const float* __restrict__ beta,
                         float* __restrict__ scale, float* __restrict__ shift, int C){
    int c = threadIdx.x; if (c >= C) return;
    const float invN = 1.f/(float)(B_*HW_);
    float mu  = sum[c]*invN;
    float var = sumsq[c]*invN - mu*mu;
    float s = gamma[c] * rsqrtf(var + 1e-5f);
    scale[c] = s;
    shift[c] = beta[c] - mu*s;
}

// ---------------------------------------------------------------------------
// Global average pool of feat -> p (B,32). One block per (b,c).
// ---------------------------------------------------------------------------
__global__ void pool_k(const float* __restrict__ feat, float* __restrict__ p){
    const int bc = blockIdx.x;
    const float* src = feat + (long)bc*HW_;
    float s = 0.f;
    for (int i=threadIdx.x; i<HW_; i+=256) s += src[i];
    #pragma unroll
    for (int off=32; off; off>>=1) s += __shfl_down(s, off, 64);
    __shared__ float red[4];
    const int lane = threadIdx.x & 63, wid = threadIdx.x >> 6;
    if (lane == 0) red[wid] = s;
    __syncthreads();
    if (threadIdx.x == 0)
        p[bc] = (red[0]+red[1]+red[2]+red[3]) * (1.f/(float)HW_);
}

// ---------------------------------------------------------------------------
// CAM MLP (32->16 celu ->16 celu ->1 relu +0.001) then gauss_win -> gk (B,8)
// ---------------------------------------------------------------------------
__global__ void sigma_k(const float* __restrict__ p,
                        const float* s1w, const float* s1b,
                        const float* s2w, const float* s2b,
                        const float* s3w, const float* s3b,
                        float* __restrict__ gk){
    const int b = threadIdx.x;
    if (b >= B_) return;
    float h1[16], h2[16];
    for (int i=0;i<16;++i){
        float t = s1b[i];
        for (int j=0;j<32;++j) t = fmaf(p[b*32+j], s1w[i*32+j], t);
        h1[i] = t > 0.f ? t : expm1f(t);          // celu(alpha=1)
    }
    for (int i=0;i<16;++i){
        float t = s2b[i];
        for (int j=0;j<16;++j) t = fmaf(h1[j], s2w[i*16+j], t);
        h2[i] = t > 0.f ? t : expm1f(t);
    }
    float t = s3b[0];
    for (int j=0;j<16;++j) t = fmaf(h2[j], s3w[j], t);
    float sigma = fmaxf(t, 0.f) + 0.001f;
    float sg = sigma + 0.2f;                      // sigma_gamma = 0.2
    float e = expf(-1.f/(2.f*sg*sg));
    float inv = 1.f/(2.f*e + 1.f);
    float a = e*inv, c = inv;                     // w1 = [a, c, a]
    float* g = gk + b*8;                          // outer(w1,w1) flat minus center
    g[0]=a*a; g[1]=a*c; g[2]=a*a; g[3]=c*a; g[4]=c*a; g[5]=a*a; g[6]=a*c; g[7]=a*a;
}

// ---------------------------------------------------------------------------
// Final: build offsets/affinities from oa3 (B,24,H,W), deform-sample fusion,
// write |.| as fp32.
// ---------------------------------------------------------------------------
__global__ void deform_k(const float* __restrict__ oa3, const float* __restrict__ fusion,
                         const float* __restrict__ gk, const float* __restrict__ aff_scale,
                         float* __restrict__ out){
    const int idx = blockIdx.x*256 + threadIdx.x;
    if (idx >= B_*HW_) return;
    const int b   = idx / HW_;
    const int pix = idx - b*HW_;
    const int y = pix / W_, x = pix - (pix/W_)*W_;
    const float inv_s = 1.f/(aff_scale[0] + 1e-5f);
    const float* base = oa3 + (long)b*24*HW_ + pix;

    float aff[8]; float sa = 0.f;
    #pragma unroll
    for (int n=0;n<8;++n){
        float a = tanhf(base[(16+n)*HW_]) * inv_s + gk[b*8+n];
        aff[n] = a; sa += fabsf(a);
    }
    sa += 1e-5f;
    sa = fmaxf(sa, 1.f);
    const float isa = 1.f/sa;
    float ssum = 0.f;
    #pragma unroll
    for (int n=0;n<8;++n){ aff[n] *= isa; ssum += aff[n]; }
    const float aff_ref = 1.f - ssum;

    const float* img = fusion + (long)b*HW_;
    float o = 0.f;
    #pragma unroll
    for (int k=0;k<9;++k){
        float dy, dx, m;
        if (k == 4){ dy = 0.f; dx = 0.f; m = aff_ref; }
        else {
            const int n = (k < 4) ? k : k-1;
            dy = base[(2*n)*HW_];        // off[:,n,0] = oa channel 2n
            dx = base[(2*n+1)*HW_];      // off[:,n,1] = oa channel 2n+1
            m  = aff[n];
        }
        float yy = (float)(y + k/3 - 1) + dy;
        float xx = (float)(x + k%3 - 1) + dx;
        float y0f = floorf(yy), x0f = floorf(xx);
        int   y0 = (int)y0f,    x0i = (int)x0f;
        float wy1 = yy - y0f, wy0 = 1.f - wy1;
        float wx1 = xx - x0f, wx0 = 1.f - wx1;
        float v00 = (y0  >=0 && y0  <H_ && x0i  >=0 && x0i  <W_) ? img[ y0   *W_ + x0i  ] : 0.f;
        float v01 = (y0  >=0 && y0  <H_ && x0i+1>=0 && x0i+1<W_) ? img[ y0   *W_ + x0i+1] : 0.f;
        float v10 = (y0+1>=0 && y0+1<H_ && x0i  >=0 && x0i  <W_) ? img[(y0+1)*W_ + x0i  ] : 0.f;
        float v11 = (y0+1>=0 && y0+1<H_ && x0i+1>=0 && x0i+1<W_) ? img[(y0+1)*W_ + x0i+1] : 0.f;
        o += m * (wy0*(wx0*v00 + wx1*v01) + wy1*(wx0*v10 + wx1*v11));
    }
    out[idx] = fabsf(o);
}

// ---------------------------------------------------------------------------
extern "C" void kernel_launch(void* const* d_in, const int* in_sizes, int n_in,
                              void* d_out, int out_size, void* d_ws, size_t ws_size,
                              hipStream_t stream){
    const float* feat    = (const float*)d_in[0];
    const float* g1_w    = (const float*)d_in[1];
    const float* g1_g    = (const float*)d_in[2];
    const float* g1_b    = (const float*)d_in[3];
    const float* g2_w    = (const float*)d_in[4];
    const float* g2_g    = (const float*)d_in[5];
    const float* g2_b    = (const float*)d_in[6];
    const float* g3_w    = (const float*)d_in[7];
    const float* g3_bias = (const float*)d_in[8];
    const float* f1_w    = (const float*)d_in[9];
    const float* f1_g    = (const float*)d_in[10];
    const float* f1_b    = (const float*)d_in[11];
    const float* f2_w    = (const float*)d_in[12];
    const float* f2_bias = (const float*)d_in[13];
    const float* s1w     = (const float*)d_in[14];
    const float* s1b     = (const float*)d_in[15];
    const float* s2w     = (const float*)d_in[16];
    const float* s2b     = (const float*)d_in[17];
    const float* s3w     = (const float*)d_in[18];
    const float* s3b     = (const float*)d_in[19];
    const float* oa1_w   = (const float*)d_in[20];
    const float* oa1_g   = (const float*)d_in[21];
    const float* oa1_b   = (const float*)d_in[22];
    const float* oa2_w   = (const float*)d_in[23];
    const float* oa2_g   = (const float*)d_in[24];
    const float* oa2_b   = (const float*)d_in[25];
    const float* oa3_w   = (const float*)d_in[26];
    const float* oa3_bias= (const float*)d_in[27];
    const float* aff_scale=(const float*)d_in[28];
    float* out = (float*)d_out;

    // workspace layout (fp32 intermediates):
    //   A1   : 32ch (f1/g1 out)                   104857600 B; later aliased by OA2 (24ch)
    //   A2   : 8ch  (g2 out, then oa1 out)         26214400 B
    //   GUID : 8ch                                 26214400 B
    //   FUS  : 1ch                                  3276800 B
    //   OA3  : 24ch                                78643200 B
    //   SM   : stats + repacked weights             ~262 KB     (total ~228.4 MiB)
    char* ws = (char*)d_ws;
    float* A1   = (float*)(ws + 0L);
    float* A2   = (float*)(ws + 104857600L);
    float* GUID = (float*)(ws + 131072000L);
    float* FUS  = (float*)(ws + 157286400L);
    float* OA3  = (float*)(ws + 160563200L);
    float* SM   = (float*)(ws + 239206400L);
    float* OA2  = A1;   // alias: A1 dead before oa2 conv writes

    float* sum   = SM;         // 5 stages * 64
    float* sq    = SM + 320;
    float* scale = SM + 640;
    float* shift = SM + 960;
    float* p     = SM + 1280;  // 256
    float* gk    = SM + 1536;  // 64
    float* w_f1 = SM + 1600;
    float* w_f2 = w_f1 + 9216;
    float* w_g1 = w_f2 + 288;
    float* w_g2 = w_g1 + 25600;
    float* w_g3 = w_g2 + 6400;
    float* w_o1 = w_g3 + 1600;
    float* w_o2 = w_o1 + 1600;
    float* w_o3 = w_o2 + 4800;

    hipMemsetAsync(sum, 0, 640*sizeof(float), stream);   // zero sum+sumsq

    auto rp = [&](const float* w, float* o, int Cout, int CinKK){
        int n = Cout*CinKK;
        repack_k<<<dim3((n+255)/256), dim3(256), 0, stream>>>(w, o, Cout, CinKK);
    };
    rp(f1_w,  w_f1, 32, 32*9);
    rp(f2_w,  w_f2,  1, 32*9);
    rp(g1_w,  w_g1, 32, 32*25);
    rp(g2_w,  w_g2,  8, 32*25);
    rp(g3_w,  w_g3,  8,  8*25);
    rp(oa1_w, w_o1,  8,  8*25);
    rp(oa2_w, w_o2, 24,  8*25);
    rp(oa3_w, w_o3, 24, 24*25);

    // sigma branch (independent)
    pool_k<<<dim3(256), dim3(256), 0, stream>>>(feat, p);
    sigma_k<<<dim3(1), dim3(64), 0, stream>>>(p, s1w, s1b, s2w, s2b, s3w, s3b, gk);

    const dim3 cgrid(10, 40, 8), cblk(256);

    // fuse branch: f1 (3x3 32->32) -> BN stats -> f2 (3x3 32->1, tanh)
    conv_k<32,32,3,false,0><<<cgrid,cblk,0,stream>>>(feat, nullptr, nullptr, w_f1, nullptr, A1);
    bn_stats_k<<<dim3(32,32),256,0,stream>>>(A1, sum+0*64, sq+0*64, 32);
    bn_fin_k<<<1,64,0,stream>>>(sum+0*64, sq+0*64, f1_g, f1_b, scale+0*64, shift+0*64, 32);
    conv_k<32, 1,3,true ,2><<<cgrid,cblk,0,stream>>>(A1, scale+0*64, shift+0*64, w_f2, f2_bias, FUS);

    // guid branch: g1 (5x5 32->32) -> g2 (5x5 32->8) -> g3 (5x5 8->8 +bias)
    conv_k<32,32,5,false,0><<<cgrid,cblk,0,stream>>>(feat, nullptr, nullptr, w_g1, nullptr, A1);
    bn_stats_k<<<dim3(32,32),256,0,stream>>>(A1, sum+1*64, sq+1*64, 32);
    bn_fin_k<<<1,64,0,stream>>>(sum+1*64, sq+1*64, g1_g, g1_b, scale+1*64, shift+1*64, 32);
    conv_k<32, 8,5,true ,0><<<cgrid,cblk,0,stream>>>(A1, scale+1*64, shift+1*64, w_g2, nullptr, A2);
    bn_stats_k<<<dim3(8,32),256,0,stream>>>(A2, sum+2*64, sq+2*64, 8);
    bn_fin_k<<<1,64,0,stream>>>(sum+2*64, sq+2*64, g2_g, g2_b, scale+2*64, shift+2*64, 8);
    conv_k< 8, 8,5,true ,1><<<cgrid,cblk,0,stream>>>(A2, scale+2*64, shift+2*64, w_g3, g3_bias, GUID);

    // off_aff branch: oa1 (5x5 8->8) -> oa2 (5x5 8->24) -> oa3 (5x5 24->24 +bias)
    conv_k< 8, 8,5,false,0><<<cgrid,cblk,0,stream>>>(GUID, nullptr, nullptr, w_o1, nullptr, A2);
    bn_stats_k<<<dim3(8,32),256,0,stream>>>(A2, sum+3*64, sq+3*64, 8);
    bn_fin_k<<<1,64,0,stream>>>(sum+3*64, sq+3*64, oa1_g, oa1_b, scale+3*64, shift+3*64, 8);
    conv_k< 8,24,5,true ,0><<<cgrid,cblk,0,stream>>>(A2, scale+3*64, shift+3*64, w_o2, nullptr, OA2);
    bn_stats_k<<<dim3(24,32),256,0,stream>>>(OA2, sum+4*64, sq+4*64, 24);
    bn_fin_k<<<1,64,0,stream>>>(sum+4*64, sq+4*64, oa2_g, oa2_b, scale+4*64, shift+4*64, 24);
    conv_k<24,24,5,true ,1><<<cgrid,cblk,0,stream>>>(OA2, scale+4*64, shift+4*64, w_o3, oa3_bias, OA3);

    // final deform-gauss filter + abs
    deform_k<<<dim3((B_*HW_+255)/256), dim3(256), 0, stream>>>(OA3, FUS, gk, aff_scale, out);
}